// Round 24
// baseline (50.971 us; speedup 1.0000x reference)
//
#include <hip/hip_runtime.h>
#include <stdint.h>

typedef unsigned int u32;
typedef unsigned long long u64;
typedef int v4i  __attribute__((ext_vector_type(4)));
typedef float v4f __attribute__((ext_vector_type(4)));
typedef int v16i __attribute__((ext_vector_type(16)));

// Binarized MLP via i8 MFMA. r24: (a) x-pack isolated into the pack dispatch
// as thread-per-word (8 independent float4 loads/thread, 1 cacheline/lane,
// BW-floor ~8us) -> rocprof finally shows its cost; (b) fused kernel at
// 2 blocks/CU: MB=32 (512 blocks), LDS 55KB (3x16KB counted-vmcnt B
// pipeline, vmcnt(4) steady / 2-ahead), A expanded IN-REGISTER per phase
// (24 VALU, r14/15-proven, mfma_v hazard nops), acts in odd-stride LDS,
// epilogue barriers lgkmcnt-only (no vmcnt drain at layer boundaries).
// Verbatim-proven: weight pack (r10/r15), expandpm (r14), A/B slice pairing
// (r19/r23), epilogue C/D map (r19), BN order, Apre, L4 (r19).

#define NB    16384
#define DIN   784
#define HID   512
#define DOUT  10
#define MB    32
#define THR   512
#define NCH   57

// ws byte offsets: W1|W2|W3 contiguous 16KB chunks 0..56, then W4, Apre, Xp
#define W1OFF 0           // chunks 0..24
#define W2OFF 409600      // chunks 25..40
#define W3OFF 671744      // chunks 41..56
#define W4OFF 933888
#define APOFF 950272      // Apre f32[3][512]
#define XPOFF 956416      // Xp u32[16384][25]

// LDS layout (bytes), total 56704 -> 2 blocks/CU
#define BUFO  0           // 3 x 16KB chunk buffers
#define A1SO  49152       // A1s u32[32*25]
#define AAO   52352       // AA  u32[32*17]
#define ABO   54528       // AB  u32[32*17]
#define LDSSZ 56704

// ------------- pack: weights->±1 i8 + Apre (r15) + x->bit-words -------------
__global__ void bmlp_pack(const float* __restrict__ x,
                          const float* __restrict__ w1, const float* __restrict__ w2,
                          const float* __restrict__ w3, const float* __restrict__ w4,
                          const float* __restrict__ g1, const float* __restrict__ v1,
                          const float* __restrict__ g2, const float* __restrict__ v2,
                          const float* __restrict__ g3, const float* __restrict__ v3,
                          char* __restrict__ ws)
{
    const int tid = threadIdx.x;
    if (blockIdx.x >= 238) {                  // x-pack: thread per (row, word)
        int xid = (blockIdx.x - 238) * 256 + tid;     // 409600 exactly
        int row = xid / 25, w = xid - row * 25;
        const float* src = x + (size_t)row * DIN + w * 32;
        u32 word = 0;
        if (w < 24) {
#pragma unroll
            for (int j = 0; j < 8; ++j) {
                v4f v = *(const v4f*)(src + 4 * j);
                word |= (v.x < 0.0f ? 1u : 0u) << (4 * j);
                word |= (v.y < 0.0f ? 1u : 0u) << (4 * j + 1);
                word |= (v.z < 0.0f ? 1u : 0u) << (4 * j + 2);
                word |= (v.w < 0.0f ? 1u : 0u) << (4 * j + 3);
            }
        } else {                              // tail word: 16 real, 16 zero pads
#pragma unroll
            for (int j = 0; j < 4; ++j) {
                v4f v = *(const v4f*)(src + 4 * j);
                word |= (v.x < 0.0f ? 1u : 0u) << (4 * j);
                word |= (v.y < 0.0f ? 1u : 0u) << (4 * j + 1);
                word |= (v.z < 0.0f ? 1u : 0u) << (4 * j + 2);
                word |= (v.w < 0.0f ? 1u : 0u) << (4 * j + 3);
            }
        }
        ((u32*)(ws + XPOFF))[row * 25 + w] = word;
        return;
    }
    int tt = blockIdx.x * 256 + tid;          // weights/Apre (r15 verbatim)
    const float* src; int base, K, dst16; bool zero = false;
    if (tt < 25600) {                         // W1
        int r = tt, ks = r >> 10, khh = (r >> 9) & 1, col = r & 511;
        base = ks * 32 + khh * 16; src = w1 + col * DIN; K = DIN; dst16 = r;
    } else if (tt < 41984) {                  // W2
        int r = tt - 25600, ks = r >> 10, khh = (r >> 9) & 1, col = r & 511;
        base = ks * 32 + khh * 16; src = w2 + col * HID; K = HID; dst16 = W2OFF / 16 + r;
    } else if (tt < 58368) {                  // W3
        int r = tt - 41984, ks = r >> 10, khh = (r >> 9) & 1, col = r & 511;
        base = ks * 32 + khh * 16; src = w3 + col * HID; K = HID; dst16 = W3OFF / 16 + r;
    } else if (tt < 59392) {                  // W4 (32-col padded, 10 real)
        int r = tt - 58368, ks = r >> 6, khh = (r >> 5) & 1, col = r & 31;
        base = ks * 32 + khh * 16; src = w4 + col * HID; K = HID; dst16 = W4OFF / 16 + r;
        zero = (col >= DOUT);
    } else {                                  // Apre (bit-exact BN scale)
        int ai = tt - 59392;
        if (ai < 1536) {
            int ly = ai >> 9, c = ai & 511;
            const float* g = (ly == 0) ? g1 : (ly == 1) ? g2 : g3;
            const float* v = (ly == 0) ? v1 : (ly == 1) ? v2 : v3;
            float eps = (ly == 2) ? 512.0f : 1e-5f;   // EPS3 source bug: 512
            float A = __fmul_rn(g[c], __fdiv_rn(1.0f, __fsqrt_rn(__fadd_rn(v[c], eps))));
            ((float*)(ws + APOFF))[ai] = A;
        }
        return;
    }
    u32 d[4] = {0u, 0u, 0u, 0u};
    if (!zero) {
#pragma unroll
        for (int j = 0; j < 16; ++j) {
            int eg = base + j;
            u32 byte = 0;                     // K-pad -> 0
            if (eg < K) byte = (src[eg] < 0.0f) ? 0xFFu : 0x01u;   // -1 / +1
            d[j >> 2] |= byte << ((j & 3) * 8);
        }
    }
    v4i val; val.x = (int)d[0]; val.y = (int)d[1]; val.z = (int)d[2]; val.w = (int)d[3];
    ((v4i*)ws)[dst16] = val;
}

// ---------------- device helpers ----------------
__device__ __forceinline__ v4i expandpm(u32 sel)    // 16 bits -> 16 ±1 bytes
{
    u32 e0 = (((sel      ) & 15u) * 0x00204081u) & 0x01010101u;
    u32 e1 = (((sel >> 4 ) & 15u) * 0x00204081u) & 0x01010101u;
    u32 e2 = (((sel >> 8 ) & 15u) * 0x00204081u) & 0x01010101u;
    u32 e3 = (((sel >> 12) & 15u) * 0x00204081u) & 0x01010101u;
    v4i r;
    r.x = (int)(0x01010101u + e0 * 254u);
    r.y = (int)(0x01010101u + e1 * 254u);
    r.z = (int)(0x01010101u + e2 * 254u);
    r.w = (int)(0x01010101u + e3 * 254u);
    return r;
}

// VALU-fed MFMA: s_nop 2 covers write->read wait states (r13 lesson, proven)
__device__ __forceinline__ void mfma_v(v16i& a, v4i af, v4i bf)
{
    asm("s_nop 2\n\tv_mfma_i32_32x32x32_i8 %0, %1, %2, %0"
        : "+a"(a) : "v"(af), "v"(bf));
}

// async global->LDS, 16B per lane
__device__ __forceinline__ void gload_lds16(const char* g, char* l)
{
    __builtin_amdgcn_global_load_lds(
        (const __attribute__((address_space(1))) void*)g,
        (__attribute__((address_space(3))) void*)l, 16, 0, 0);
}

// stage 16KB chunk g into buffer ti: wave wv takes 2KB
__device__ __forceinline__ void stage_chunk(const char* __restrict__ ws,
                                            char* smem, int g, int ti,
                                            int wv, int lane)
{
    const char* src = ws + (size_t)g * 16384 + wv * 2048 + lane * 16;
    char* dst = smem + BUFO + ti * 16384 + wv * 2048;
    gload_lds16(src, dst);
    gload_lds16(src + 1024, dst + 1024);
}

// counted-vmcnt phase: stage g+2 -> buf[(bi+2)%3]; wait chunk g; in-register
// A expand; 2 MFMA; barriers raw (fences stop LDS-read hoisting, rule #18).
#define PHASE(g_, ci_, ACT, STRIDE, NSTR)                                  \
  {                                                                        \
    if ((g_) + 2 < NCH) {                                                  \
        int ti = (bi == 0) ? 2 : bi - 1;                                   \
        stage_chunk(ws, smem, (g_) + 2, ti, wv, lane);                     \
    }                                                                      \
    asm volatile("s_waitcnt vmcnt(" NSTR ")" ::: "memory");                \
    __builtin_amdgcn_s_barrier();                                          \
    asm volatile("" ::: "memory");                                         \
    u32 aw0 = (ACT)[l31 * (STRIDE) + (ci_)];                               \
    v4i af0 = expandpm((aw0 >> kh16) & 0xFFFFu);                           \
    const char* bp = smem + BUFO + bi * 16384 + kh * 8192 + colb;          \
    v4i bf0 = *(const v4i*)(bp);                                           \
    v4i bf1 = *(const v4i*)(bp + 512);                                     \
    mfma_v(acc[0], af0, bf0);                                              \
    mfma_v(acc[1], af0, bf1);                                              \
    asm volatile("" ::: "memory");                                         \
    __builtin_amdgcn_s_barrier();                                          \
    bi = (bi == 2) ? 0 : bi + 1;                                           \
  }

// lgkmcnt-only barrier: LDS writes visible without draining vmcnt prefetch
#define LBAR()                                                             \
    asm volatile("s_waitcnt lgkmcnt(0)" ::: "memory");                     \
    __builtin_amdgcn_s_barrier();                                          \
    asm volatile("" ::: "memory");

// BN + sign -> ballot -> bit-packed acts (r19 epilogue, params preloaded)
__device__ __forceinline__ void epilogue(v16i acc[2], u32* dst,
    const float* pb, const float* pm, const float* pe, const float* pA,
    int lane, int wv)
{
    asm volatile("s_nop 7\ns_nop 7\ns_nop 7"        // MFMA->read fence
        : "+a"(acc[0]), "+a"(acc[1]));
    const int l31 = lane & 31;
    const int rAdd = (lane & 32) >> 3;              // +4 for hi lanes
#pragma unroll
    for (int rg = 0; rg < 16; ++rg) {
        int rowMe = (rg & 3) + 8 * (rg >> 2) + rAdd;    // 0..31
#pragma unroll
        for (int c = 0; c < 2; ++c) {
            float xl = __fadd_rn((float)acc[c][rg], pb[c]);
            float y  = __fadd_rn(__fmul_rn(__fsub_rn(xl, pm[c]), pA[c]), pe[c]);
            u64 bal = __ballot(y < 0.0f);           // bit=1 <=> -1
            if (!(lane & 31))                       // lanes 0 and 32
                dst[rowMe * 17 + (wv * 2 + c)] = (u32)(bal >> ((lane >> 5) << 5));
            acc[c][rg] = 0;
        }
    }
}

__global__ __launch_bounds__(THR)
void bmlp_fused(const char* __restrict__ ws,
                const float* __restrict__ b1, const float* __restrict__ m1, const float* __restrict__ be1,
                const float* __restrict__ b2, const float* __restrict__ m2, const float* __restrict__ be2,
                const float* __restrict__ b3, const float* __restrict__ m3, const float* __restrict__ be3,
                const float* __restrict__ b4, float* __restrict__ out)
{
    extern __shared__ __align__(16) char smem[];
    u32* A1s = (u32*)(smem + A1SO);
    u32* AA  = (u32*)(smem + AAO);
    u32* AB  = (u32*)(smem + ABO);

    const int tid = threadIdx.x, lane = tid & 63, wv = tid >> 6;   // wv 0..7
    const int l31 = lane & 31;
    const int kh16 = (lane & 32) >> 1;
    const int kh = kh16 >> 4;
    const int colb = (wv * 64 + l31) * 16;
    const int row0 = blockIdx.x * MB;
    const float* Ap = (const float*)(ws + APOFF);
    const u32* Xp = (const u32*)(ws + XPOFF);

    // prologue: stage chunks 0,1 (drained once by the syncthreads below)
    stage_chunk(ws, smem, 0, 0, wv, lane);
    stage_chunk(ws, smem, 1, 1, wv, lane);

    // preload BN params
    float b1p[2], m1p[2], e1p[2], A1p[2];
    float b2p[2], m2p[2], e2p[2], A2p[2];
    float b3p[2], m3p[2], e3p[2], A3p[2];
#pragma unroll
    for (int c = 0; c < 2; ++c) {
        int col = wv * 64 + c * 32 + l31;
        b1p[c] = b1[col]; m1p[c] = m1[col]; e1p[c] = be1[col]; A1p[c] = Ap[col];
        b2p[c] = b2[col]; m2p[c] = m2[col]; e2p[c] = be2[col]; A2p[c] = Ap[512 + col];
        b3p[c] = b3[col]; m3p[c] = m3[col]; e3p[c] = be3[col]; A3p[c] = Ap[1024 + col];
    }

    // stage this block's act bit-words (32 rows x 25 words, coalesced)
    for (int i = tid; i < MB * 25; i += THR)
        A1s[i] = Xp[(size_t)row0 * 25 + i];
    __syncthreads();                                 // acts + chunks 0,1 ready

    v16i acc[2];
#pragma unroll
    for (int c = 0; c < 2; ++c)
#pragma unroll
        for (int i = 0; i < 16; ++i) acc[c][i] = 0;

    int bi = 0;
    // ---- L1: chunks 0..24 ----
#pragma unroll 1
    for (int ci = 0; ci < 25; ++ci) { PHASE(ci, ci, A1s, 25, "4"); }
    epilogue(acc, AA, b1p, m1p, e1p, A1p, lane, wv);
    LBAR();

    // ---- L2: chunks 25..40 ----
#pragma unroll 1
    for (int ci = 0; ci < 16; ++ci) { PHASE(25 + ci, ci, AA, 17, "4"); }
    epilogue(acc, AB, b2p, m2p, e2p, A2p, lane, wv);
    LBAR();

    // ---- L3: chunks 41..56 (eps=512 folded into Apre) ----
#pragma unroll 1
    for (int ci = 0; ci < 14; ++ci) { PHASE(41 + ci, ci, AB, 17, "4"); }
    { PHASE(55, 14, AB, 17, "2"); }
    { PHASE(56, 15, AB, 17, "0"); }
    epilogue(acc, AA, b3p, m3p, e3p, A3p, lane, wv);
    LBAR();

    // ---- L4: wave 0 only; out = dot + b4 (r19 verbatim) ----
    if (wv == 0) {
#pragma unroll
        for (int ks = 0; ks < 16; ++ks) {
            u32 aw = AA[l31 * 17 + ks];
            v4i af = expandpm((aw >> kh16) & 0xFFFFu);
            v4i bf = *(const v4i*)(ws + W4OFF + (size_t)((ks * 2 + kh) * 32 + l31) * 16);
            mfma_v(acc[0], af, bf);
        }
        asm volatile("s_nop 7\ns_nop 7\ns_nop 7" : "+a"(acc[0]));
        const int rAdd = (lane & 32) >> 3;
        if (l31 < DOUT) {
            float pb4 = b4[l31];
#pragma unroll
            for (int rg = 0; rg < 16; ++rg) {
                int rowE = (rg & 3) + 8 * (rg >> 2) + rAdd;     // 0..31
                out[(size_t)(row0 + rowE) * DOUT + l31] =
                    __fadd_rn((float)acc[0][rg], pb4);
            }
        }
    }
}

extern "C" void kernel_launch(void* const* d_in, const int* in_sizes, int n_in,
                              void* d_out, int out_size, void* d_ws, size_t ws_size,
                              hipStream_t stream)
{
    const float* x   = (const float*)d_in[0];
    const float* w1  = (const float*)d_in[1];
    const float* b1  = (const float*)d_in[2];
    const float* g1  = (const float*)d_in[3];
    const float* be1 = (const float*)d_in[4];
    const float* m1  = (const float*)d_in[5];
    const float* v1  = (const float*)d_in[6];
    const float* w2  = (const float*)d_in[7];
    const float* b2  = (const float*)d_in[8];
    const float* g2  = (const float*)d_in[9];
    const float* be2 = (const float*)d_in[10];
    const float* m2  = (const float*)d_in[11];
    const float* v2  = (const float*)d_in[12];
    const float* w3  = (const float*)d_in[13];
    const float* b3  = (const float*)d_in[14];
    const float* g3  = (const float*)d_in[15];
    const float* be3 = (const float*)d_in[16];
    const float* m3  = (const float*)d_in[17];
    const float* v3  = (const float*)d_in[18];
    const float* w4  = (const float*)d_in[19];
    const float* b4  = (const float*)d_in[20];
    float* out = (float*)d_out;
    char* ws = (char*)d_ws;                 // ~2.6 MB used

    // one dispatch: 238 weight/Apre blocks + 1600 x-pack blocks
    bmlp_pack<<<dim3(238 + NB * 25 / 256), 256, 0, stream>>>(
        x, w1, w2, w3, w4, g1, v1, g2, v2, g3, v3, ws);

    bmlp_fused<<<dim3(NB / MB), THR, LDSSZ, stream>>>(
        ws,
        b1, m1, be1,
        b2, m2, be2,
        b3, m3, be3,
        b4, out);
}